// Round 1
// baseline (531.525 us; speedup 1.0000x reference)
//
#include <hip/hip_runtime.h>

#define N_ITEMS 200000
#define DIM 128
#define EPSV 1e-8f
#define INV_TEMP 10.0f

// Stable softplus, matches jax.nn.softplus = logaddexp(x, 0)
__device__ __forceinline__ float softplus_f(float x) {
    return fmaxf(x, 0.0f) + log1pf(expf(-fabsf(x)));
}

__global__ void mvr_init_ws(float* ws) {
    if (threadIdx.x < 3) ws[threadIdx.x] = 0.0f;
}

__global__ __launch_bounds__(256) void mvr_main(
    const float* __restrict__ g1, const float* __restrict__ g2,
    const float* __restrict__ s1, const float* __restrict__ s2,
    const float* __restrict__ att_w,
    const int* __restrict__ neg_g, const int* __restrict__ neg_s,
    const int* __restrict__ neg_c,
    float* __restrict__ out, float* __restrict__ loss_acc)
{
    const int lane = threadIdx.x & 63;
    const int wave = threadIdx.x >> 6;
    const int wavesPerBlock = blockDim.x >> 6;     // 4
    const int stride = gridDim.x * wavesPerBlock;
    int item = blockIdx.x * wavesPerBlock + wave;

    // att_w as two 128-float halves; lane holds 2 elems of each
    const float2 wlo = ((const float2*)att_w)[lane];
    const float2 whi = ((const float2*)att_w)[64 + lane];

    float accG = 0.0f, accS = 0.0f, accC = 0.0f;

    const float2* G1p = (const float2*)g1;
    const float2* G2p = (const float2*)g2;
    const float2* S1p = (const float2*)s1;
    const float2* S2p = (const float2*)s2;
    float2* Op = (float2*)out;

    for (; item < N_ITEMS; item += stride) {
        const size_t rb = (size_t)item * (DIM / 2);
        float2 G1 = G1p[rb + lane];
        float2 G2 = G2p[rb + lane];
        float2 S1 = S1p[rb + lane];
        float2 S2 = S2p[rb + lane];
        const int jg = neg_g[item];
        const int js = neg_s[item];
        const int jc = neg_c[item];
        float2 G2n = G2p[(size_t)jg * (DIM / 2) + lane];
        float2 S2n = S2p[(size_t)js * (DIM / 2) + lane];
        float2 S1c = S1p[(size_t)jc * (DIM / 2) + lane];
        float2 S2c = S2p[(size_t)jc * (DIM / 2) + lane];

        float2 GA  = make_float2(0.5f * (G1.x + G2.x), 0.5f * (G1.y + G2.y));
        float2 SA  = make_float2(0.5f * (S1.x + S2.x), 0.5f * (S1.y + S2.y));
        float2 SAN = make_float2(0.5f * (S1c.x + S2c.x), 0.5f * (S1c.y + S2c.y));

        float v[16];
        v[0]  = G1.x * G2.x  + G1.y * G2.y;    // g1.g2
        v[1]  = G1.x * G1.x  + G1.y * G1.y;    // |g1|^2
        v[2]  = G2.x * G2.x  + G2.y * G2.y;    // |g2|^2
        v[3]  = G1.x * G2n.x + G1.y * G2n.y;   // g1.g2[neg]
        v[4]  = G2n.x * G2n.x + G2n.y * G2n.y; // |g2[neg]|^2
        v[5]  = S1.x * S2.x  + S1.y * S2.y;
        v[6]  = S1.x * S1.x  + S1.y * S1.y;
        v[7]  = S2.x * S2.x  + S2.y * S2.y;
        v[8]  = S1.x * S2n.x + S1.y * S2n.y;
        v[9]  = S2n.x * S2n.x + S2n.y * S2n.y;
        v[10] = GA.x * SA.x  + GA.y * SA.y;    // ga.sa
        v[11] = GA.x * GA.x  + GA.y * GA.y;    // |ga|^2
        v[12] = SA.x * SA.x  + SA.y * SA.y;    // |sa|^2
        v[13] = GA.x * SAN.x + GA.y * SAN.y;   // ga.sa[neg]
        v[14] = SAN.x * SAN.x + SAN.y * SAN.y; // |sa[neg]|^2
        v[15] = GA.x * wlo.x + GA.y * wlo.y + SA.x * whi.x + SA.y * whi.y; // att dot

        // Butterfly reduction: every lane ends with the full sums
        #pragma unroll
        for (int off = 32; off > 0; off >>= 1) {
            #pragma unroll
            for (int k = 0; k < 16; k++)
                v[k] += __shfl_xor(v[k], off, 64);
        }

        const float ng1 = sqrtf(v[1]), ng2 = sqrtf(v[2]), ngn = sqrtf(v[4]);
        const float cgp = v[0] / fmaxf(ng1 * ng2, EPSV);
        const float cgn = v[3] / fmaxf(ng1 * ngn, EPSV);
        accG += softplus_f((cgn - cgp) * INV_TEMP);

        const float ns1 = sqrtf(v[6]), ns2 = sqrtf(v[7]), nsn = sqrtf(v[9]);
        const float csp = v[5] / fmaxf(ns1 * ns2, EPSV);
        const float csn = v[8] / fmaxf(ns1 * nsn, EPSV);
        accS += softplus_f((csn - csp) * INV_TEMP);

        const float nga = sqrtf(v[11]), nsa = sqrtf(v[12]), nsan = sqrtf(v[14]);
        const float ccp = v[10] / fmaxf(nga * nsa, EPSV);
        const float ccn = v[13] / fmaxf(nga * nsan, EPSV);
        accC += softplus_f((ccn - ccp) * INV_TEMP);

        const float alpha = 1.0f / (1.0f + expf(-v[15]));
        float2 o;
        o.x = alpha * GA.x + (1.0f - alpha) * SA.x;
        o.y = alpha * GA.y + (1.0f - alpha) * SA.y;
        Op[rb + lane] = o;
    }

    // Block-level reduction of the three loss partials, then 3 atomics/block
    __shared__ float sh[4][3];
    if (lane == 0) {
        sh[wave][0] = accG;
        sh[wave][1] = accS;
        sh[wave][2] = accC;
    }
    __syncthreads();
    if (threadIdx.x == 0) {
        float a = 0.0f, b = 0.0f, c = 0.0f;
        for (int w = 0; w < wavesPerBlock; w++) {
            a += sh[w][0]; b += sh[w][1]; c += sh[w][2];
        }
        atomicAdd(&loss_acc[0], a);
        atomicAdd(&loss_acc[1], b);
        atomicAdd(&loss_acc[2], c);
    }
}

__global__ void mvr_finalize(const float* __restrict__ loss_acc,
                             float* __restrict__ out_scalar) {
    if (threadIdx.x == 0) {
        out_scalar[0] = (loss_acc[0] + loss_acc[1] + loss_acc[2]) * (1.0f / (float)N_ITEMS);
    }
}

extern "C" void kernel_launch(void* const* d_in, const int* in_sizes, int n_in,
                              void* d_out, int out_size, void* d_ws, size_t ws_size,
                              hipStream_t stream) {
    const float* g1    = (const float*)d_in[0];
    const float* g2    = (const float*)d_in[1];
    const float* s1    = (const float*)d_in[2];
    const float* s2    = (const float*)d_in[3];
    const float* att_w = (const float*)d_in[4];
    const int*   neg_g = (const int*)d_in[5];
    const int*   neg_s = (const int*)d_in[6];
    const int*   neg_c = (const int*)d_in[7];
    float* out = (float*)d_out;
    float* ws  = (float*)d_ws;   // 3 floats: loss partial sums

    mvr_init_ws<<<1, 64, 0, stream>>>(ws);
    mvr_main<<<2048, 256, 0, stream>>>(g1, g2, s1, s2, att_w,
                                       neg_g, neg_s, neg_c, out, ws);
    mvr_finalize<<<1, 64, 0, stream>>>(ws, out + (size_t)N_ITEMS * DIM);
}

// Round 2
// 461.011 us; speedup vs baseline: 1.1530x; 1.1530x over previous
//
#include <hip/hip_runtime.h>

#define N_ITEMS 200000
#define EPSV 1e-8f
#define INV_TEMP 10.0f

// Stable softplus, matches jax.nn.softplus = logaddexp(x, 0)
__device__ __forceinline__ float softplus_f(float x) {
    return fmaxf(x, 0.0f) + log1pf(expf(-fabsf(x)));
}

__device__ __forceinline__ float dot8(const float4& a0, const float4& a1,
                                      const float4& b0, const float4& b1) {
    return a0.x * b0.x + a0.y * b0.y + a0.z * b0.z + a0.w * b0.w +
           a1.x * b1.x + a1.y * b1.y + a1.z * b1.z + a1.w * b1.w;
}

__device__ __forceinline__ float4 avg4(const float4& a, const float4& b) {
    return make_float4(0.5f * (a.x + b.x), 0.5f * (a.y + b.y),
                       0.5f * (a.z + b.z), 0.5f * (a.w + b.w));
}

__global__ void mvr_init_ws(float* ws) {
    if (threadIdx.x < 3) ws[threadIdx.x] = 0.0f;
}

// 16 lanes per item, 8 floats (two float4) per lane → 4 items per wave.
// Butterfly reduction: 4 steps (xor 8,4,2,1) instead of 6 → 16 DS ops/item
// instead of 96 (the R1 bottleneck: ds_swizzle on the shared LDS pipe).
__global__ __launch_bounds__(256) void mvr_main(
    const float* __restrict__ g1, const float* __restrict__ g2,
    const float* __restrict__ s1, const float* __restrict__ s2,
    const float* __restrict__ att_w,
    const int* __restrict__ neg_g, const int* __restrict__ neg_s,
    const int* __restrict__ neg_c,
    float* __restrict__ out, float* __restrict__ loss_acc)
{
    const int tid = threadIdx.x;
    const int lane = tid & 63;
    const int g = lane >> 4;        // item group within wave (0..3)
    const int l = lane & 15;        // lane within group
    const int wavesPerBlock = blockDim.x >> 6;
    const int waveId = blockIdx.x * wavesPerBlock + (tid >> 6);
    const int waveStride = gridDim.x * wavesPerBlock;

    // att_w: 256 floats = 64 float4. ga-half: float4 idx l, 16+l; sa-half: 32+l, 48+l.
    const float4* W = (const float4*)att_w;
    const float4 wa0 = W[l], wa1 = W[16 + l];
    const float4 wb0 = W[32 + l], wb1 = W[48 + l];

    const float4* G1p = (const float4*)g1;
    const float4* G2p = (const float4*)g2;
    const float4* S1p = (const float4*)s1;
    const float4* S2p = (const float4*)s2;
    float4* Op = (float4*)out;

    float accG = 0.0f, accS = 0.0f, accC = 0.0f;

    // N_ITEMS divisible by 4 → item = base + g always < N_ITEMS when base < N_ITEMS
    for (int base = waveId * 4; base < N_ITEMS; base += waveStride * 4) {
        const int item = base + g;
        const size_t rb = (size_t)item * 32;   // row in float4 units (128 floats)

        float4 G1a = G1p[rb + l], G1b = G1p[rb + 16 + l];
        float4 G2a = G2p[rb + l], G2b = G2p[rb + 16 + l];
        float4 S1a = S1p[rb + l], S1b = S1p[rb + 16 + l];
        float4 S2a = S2p[rb + l], S2b = S2p[rb + 16 + l];

        const int jg = neg_g[item];
        const int js = neg_s[item];
        const int jc = neg_c[item];
        const size_t rg = (size_t)jg * 32, rs = (size_t)js * 32, rc = (size_t)jc * 32;
        float4 Gna = G2p[rg + l], Gnb = G2p[rg + 16 + l];
        float4 Sna = S2p[rs + l], Snb = S2p[rs + 16 + l];
        float4 C1a = S1p[rc + l], C1b = S1p[rc + 16 + l];
        float4 C2a = S2p[rc + l], C2b = S2p[rc + 16 + l];

        float4 GAa = avg4(G1a, G2a), GAb = avg4(G1b, G2b);
        float4 SAa = avg4(S1a, S2a), SAb = avg4(S1b, S2b);
        float4 CNa = avg4(C1a, C2a), CNb = avg4(C1b, C2b);

        float v[16];
        v[0]  = dot8(G1a, G1b, G2a, G2b);   // g1.g2
        v[1]  = dot8(G1a, G1b, G1a, G1b);   // |g1|^2
        v[2]  = dot8(G2a, G2b, G2a, G2b);   // |g2|^2
        v[3]  = dot8(G1a, G1b, Gna, Gnb);   // g1.g2[neg]
        v[4]  = dot8(Gna, Gnb, Gna, Gnb);   // |g2[neg]|^2
        v[5]  = dot8(S1a, S1b, S2a, S2b);
        v[6]  = dot8(S1a, S1b, S1a, S1b);
        v[7]  = dot8(S2a, S2b, S2a, S2b);
        v[8]  = dot8(S1a, S1b, Sna, Snb);
        v[9]  = dot8(Sna, Snb, Sna, Snb);
        v[10] = dot8(GAa, GAb, SAa, SAb);   // ga.sa
        v[11] = dot8(GAa, GAb, GAa, GAb);   // |ga|^2
        v[12] = dot8(SAa, SAb, SAa, SAb);   // |sa|^2
        v[13] = dot8(GAa, GAb, CNa, CNb);   // ga.sa[neg]
        v[14] = dot8(CNa, CNb, CNa, CNb);   // |sa[neg]|^2
        v[15] = dot8(GAa, GAb, wa0, wa1) + dot8(SAa, SAb, wb0, wb1); // att dot

        // Butterfly over the 16 lanes of the group; every lane gets the sums.
        #pragma unroll
        for (int off = 8; off > 0; off >>= 1) {
            #pragma unroll
            for (int k = 0; k < 16; k++)
                v[k] += __shfl_xor(v[k], off, 64);
        }

        const float ng1 = sqrtf(v[1]), ng2 = sqrtf(v[2]), ngn = sqrtf(v[4]);
        const float cgp = v[0] / fmaxf(ng1 * ng2, EPSV);
        const float cgn = v[3] / fmaxf(ng1 * ngn, EPSV);
        accG += softplus_f((cgn - cgp) * INV_TEMP);

        const float ns1 = sqrtf(v[6]), ns2 = sqrtf(v[7]), nsn = sqrtf(v[9]);
        const float csp = v[5] / fmaxf(ns1 * ns2, EPSV);
        const float csn = v[8] / fmaxf(ns1 * nsn, EPSV);
        accS += softplus_f((csn - csp) * INV_TEMP);

        const float nga = sqrtf(v[11]), nsa = sqrtf(v[12]), nsan = sqrtf(v[14]);
        const float ccp = v[10] / fmaxf(nga * nsa, EPSV);
        const float ccn = v[13] / fmaxf(nga * nsan, EPSV);
        accC += softplus_f((ccn - ccp) * INV_TEMP);

        const float alpha = 1.0f / (1.0f + expf(-v[15]));
        float4 o0, o1;
        o0.x = SAa.x + alpha * (GAa.x - SAa.x);
        o0.y = SAa.y + alpha * (GAa.y - SAa.y);
        o0.z = SAa.z + alpha * (GAa.z - SAa.z);
        o0.w = SAa.w + alpha * (GAa.w - SAa.w);
        o1.x = SAb.x + alpha * (GAb.x - SAb.x);
        o1.y = SAb.y + alpha * (GAb.y - SAb.y);
        o1.z = SAb.z + alpha * (GAb.z - SAb.z);
        o1.w = SAb.w + alpha * (GAb.w - SAb.w);
        Op[rb + l] = o0;
        Op[rb + 16 + l] = o1;
    }

    // All 16 lanes of a group hold identical acc values → summing across
    // groups (xor 16, 32) gives each lane the exact sum of the 4 group values.
    accG += __shfl_xor(accG, 16, 64); accG += __shfl_xor(accG, 32, 64);
    accS += __shfl_xor(accS, 16, 64); accS += __shfl_xor(accS, 32, 64);
    accC += __shfl_xor(accC, 16, 64); accC += __shfl_xor(accC, 32, 64);

    __shared__ float sh[4][3];
    const int wave = tid >> 6;
    if (lane == 0) {
        sh[wave][0] = accG;
        sh[wave][1] = accS;
        sh[wave][2] = accC;
    }
    __syncthreads();
    if (tid == 0) {
        float a = 0.0f, b = 0.0f, c = 0.0f;
        for (int w = 0; w < wavesPerBlock; w++) {
            a += sh[w][0]; b += sh[w][1]; c += sh[w][2];
        }
        atomicAdd(&loss_acc[0], a);
        atomicAdd(&loss_acc[1], b);
        atomicAdd(&loss_acc[2], c);
    }
}

__global__ void mvr_finalize(const float* __restrict__ loss_acc,
                             float* __restrict__ out_scalar) {
    if (threadIdx.x == 0) {
        out_scalar[0] = (loss_acc[0] + loss_acc[1] + loss_acc[2]) * (1.0f / (float)N_ITEMS);
    }
}

extern "C" void kernel_launch(void* const* d_in, const int* in_sizes, int n_in,
                              void* d_out, int out_size, void* d_ws, size_t ws_size,
                              hipStream_t stream) {
    const float* g1    = (const float*)d_in[0];
    const float* g2    = (const float*)d_in[1];
    const float* s1    = (const float*)d_in[2];
    const float* s2    = (const float*)d_in[3];
    const float* att_w = (const float*)d_in[4];
    const int*   neg_g = (const int*)d_in[5];
    const int*   neg_s = (const int*)d_in[6];
    const int*   neg_c = (const int*)d_in[7];
    float* out = (float*)d_out;
    float* ws  = (float*)d_ws;   // 3 floats: loss partial sums

    mvr_init_ws<<<1, 64, 0, stream>>>(ws);
    // 3125 blocks × 4 waves × 4 items/wave = 50000 items/sweep → exactly 4 sweeps
    mvr_main<<<3125, 256, 0, stream>>>(g1, g2, s1, s2, att_w,
                                       neg_g, neg_s, neg_c, out, ws);
    mvr_finalize<<<1, 64, 0, stream>>>(ws, out + (size_t)N_ITEMS * 128);
}